// Round 16
// baseline (324.933 us; speedup 1.0000x reference)
//
#include <hip/hip_runtime.h>
#include <stdint.h>

typedef __attribute__((ext_vector_type(4))) float f32x4;
typedef __attribute__((ext_vector_type(8))) short bf16x8;

#define MFMA_BF16 __builtin_amdgcn_mfma_f32_16x16x32_bf16

__device__ __forceinline__ unsigned short f2bf(float f) {
  union { float f; uint32_t u; } a; a.f = f;
  uint32_t u = a.u;
  uint32_t r = (u + 0x7FFFu + ((u >> 16) & 1u)) >> 16;
  return (unsigned short)r;
}

// Merged pack.
// q in [0, 4194304): A chunks (8B): [x|h] -> bf16 A[4096][4096] row-major.
// q in [4194304, 8388608): W chunks (16B) -> FRAGMENT-LINEAR Wp2 (64 MB):
//   wq -> lane=wq&63, fi=(wq>>6)&7 (ni=fi>>1 gate, kk=fi&1), wn=(wq>>9)&3,
//         T=(wq>>11)&63, bn=wq>>17.
//   lane holds W_gate[H][k..k+7], H = bn*64+wn*16+(lane&15),
//   k = T*64 + kk*32 + (lane>>4)*8  (k<2048 -> Wx, else Wh at k-2048).
__global__ void pack_all_kernel(const float4* __restrict__ x, const float4* __restrict__ hh,
                                const float* __restrict__ Wii, const float* __restrict__ Wif,
                                const float* __restrict__ Wig, const float* __restrict__ Wio,
                                const float* __restrict__ Whi, const float* __restrict__ Whf,
                                const float* __restrict__ Whg, const float* __restrict__ Who,
                                ushort4* __restrict__ A, ushort* __restrict__ Wp2) {
  const int total = 8388608;
  for (int q = blockIdx.x * blockDim.x + threadIdx.x; q < total; q += gridDim.x * blockDim.x) {
    if (q < 4194304) {
      int row = q >> 10, cq = q & 1023;
      float4 v = (cq < 512) ? x[row * 512 + cq] : hh[row * 512 + (cq - 512)];
      ushort4 o; o.x = f2bf(v.x); o.y = f2bf(v.y); o.z = f2bf(v.z); o.w = f2bf(v.w);
      A[q] = o;
    } else {
      int wq = q - 4194304;
      int lane = wq & 63;
      int fi = (wq >> 6) & 7;
      int wn = (wq >> 9) & 3;
      int T = (wq >> 11) & 63;
      int bn = wq >> 17;
      int ni = fi >> 1, kk = fi & 1;
      int H = (bn << 6) | (wn << 4) | (lane & 15);
      int k = (T << 6) | (kk << 5) | ((lane >> 4) << 3);
      const float* src;
      int kloc = k;
      if (k < 2048) { src = (ni == 0) ? Wii : (ni == 1) ? Wif : (ni == 2) ? Wig : Wio; }
      else { src = (ni == 0) ? Whi : (ni == 1) ? Whf : (ni == 2) ? Whg : Who; kloc = k - 2048; }
      const float4 v0 = *(const float4*)&src[(size_t)H * 2048 + kloc];
      const float4 v1 = *(const float4*)&src[(size_t)H * 2048 + kloc + 4];
      bf16x8 o;
      o[0] = (short)f2bf(v0.x); o[1] = (short)f2bf(v0.y);
      o[2] = (short)f2bf(v0.z); o[3] = (short)f2bf(v0.w);
      o[4] = (short)f2bf(v1.x); o[5] = (short)f2bf(v1.y);
      o[6] = (short)f2bf(v1.z); o[7] = (short)f2bf(v1.w);
      *(bf16x8*)&Wp2[(size_t)wq * 8] = o;
    }
  }
}

// B-DIRECT GEMM: 256x256 tile, BK=64, 8 waves (2Mx4N), per-wave 128x64.
// B fragments load straight from global (fragment-linear Wp2, coalesced
// 1 KiB/instr, L2-resident panel) into registers, prefetched 1 tile ahead
// (wave-private -> no barriers). Only A goes through LDS (2 x 32 KiB bufs,
// proven XOR-chunk 0-conflict scheme). One sync point per tile
// (vmcnt(0)+barrier; staging targets the alternate buffer -> WAR-safe).
#define AS1 __attribute__((address_space(1)))
#define AS3 __attribute__((address_space(3)))
#define GLD(srcp, dstE)                                                         \
  __builtin_amdgcn_global_load_lds((const AS1 void*)(srcp),                     \
                                   (AS3 void*)(&smem[dstE]), 16, 0, 0)

// Stage A(tile at k-offset kO_) into LDS buffer dstB_: 4 gloads/wave.
#define STGA(kO_, dstB_)                                                        \
  _Pragma("unroll") for (int j = 0; j < 4; ++j)                                 \
    GLD(aS + (size_t)j * 32768 + (kO_), (dstB_) + w * 2048 + j * 512)

// Load the 8 B fragments of tile T_ into register set B_.
#define LDB(T_, B_)                                                             \
  {                                                                             \
    const ushort* bp_ = bFrag + (size_t)(T_) * 16384;                           \
    _Pragma("unroll") for (int f = 0; f < 8; ++f)                               \
      B_[f] = *(const bf16x8*)&bp_[f * 512];                                    \
  }

// Read 4 A fragments (rows MIBASE..MIBASE+3 x 16) both kk from LDS.
#define RDA(bufE_, MIBASE, AF_)                                                 \
  _Pragma("unroll") for (int m = 0; m < 4; ++m) {                               \
    AF_[m][0] = *(const bf16x8*)&smem[(bufE_) + aRb + ((MIBASE) + m) * 1024 + colE0]; \
    AF_[m][1] = *(const bf16x8*)&smem[(bufE_) + aRb + ((MIBASE) + m) * 1024 + colE1]; \
  }

// 32 MFMA: af set (4 m-frags) x all 4 ni x 2 kk.
#define Q32(AROW, AF_, B_)                                                      \
  __builtin_amdgcn_s_setprio(1);                                                \
  _Pragma("unroll") for (int m = 0; m < 4; ++m)                                 \
    _Pragma("unroll") for (int ni = 0; ni < 4; ++ni) {                          \
      acc[(AROW) + m][ni] = MFMA_BF16(AF_[m][0], B_[ni * 2], acc[(AROW) + m][ni], 0, 0, 0); \
      acc[(AROW) + m][ni] = MFMA_BF16(AF_[m][1], B_[ni * 2 + 1], acc[(AROW) + m][ni], 0, 0, 0); \
    }                                                                           \
  __builtin_amdgcn_s_setprio(0);

#define TILEX(T_, BUFE_, NBUFE_, BCUR, BNXT, LAST)                              \
  {                                                                             \
    if (!(LAST)) { LDB((T_) + 1, BNXT); STGA(((T_) + 1) << 6, NBUFE_); }        \
    bf16x8 af[4][2];                                                            \
    RDA(BUFE_, 0, af);                                                          \
    Q32(0, af, BCUR);                                                           \
    RDA(BUFE_, 4, af);                                                          \
    Q32(4, af, BCUR);                                                           \
    if (!(LAST)) {                                                              \
      asm volatile("s_waitcnt vmcnt(0)" ::: "memory");                          \
      __builtin_amdgcn_s_barrier();                                             \
    }                                                                           \
  }

__global__ __launch_bounds__(512, 2)
void lstm_gemm_kernel(const ushort* __restrict__ A, const ushort* __restrict__ Wp2,
                      const float* __restrict__ c,
                      const float* __restrict__ bii, const float* __restrict__ bif_,
                      const float* __restrict__ big_, const float* __restrict__ bio_,
                      const float* __restrict__ bhi, const float* __restrict__ bhf,
                      const float* __restrict__ bhg, const float* __restrict__ bho,
                      float* __restrict__ out) {
  __shared__ ushort smem[32768];  // A only: 2 bufs x [256 rows][64 elems] = 64 KiB
  const int tid = threadIdx.x;
  const int lane = tid & 63, w = tid >> 6;
  const int wm = w >> 2, wn = w & 3;

  // bn-major XCD mapping: XCD x owns bn in [x*4, x*4+4) x all 16 bm;
  // concurrent blocks/XCD span ~2 B-panels (4 MB, L2-resident).
  const int bid = blockIdx.x;
  const int xcd = bid & 7, qq = bid >> 3;
  const int bn = (xcd << 2) | (qq >> 4);
  const int bm = qq & 15;

  const int laneRow = lane & 15, lane16 = lane >> 4;
  const int lr7 = laneRow & 7;
  const int colE0 = (lane16 ^ lr7) << 3;         // phys chunk elems, kk=0
  const int colE1 = ((4 + lane16) ^ lr7) << 3;   // kk=1
  const int aRb = (wm * 128 + laneRow) * 64;     // + buf + mi*1024 + colE

  // A DMA: wave w stages rows 32w..32w+31 (4 gloads x 8 rows); lane l ->
  // row +(l>>3), phys chunk l&7 holding logical (l&7)^((l>>3)&7).
  const int chunkOff = ((lane & 7) ^ (lane >> 3)) << 3;
  const ushort* aS = A + (size_t)(bm * 256 + 32 * w + (lane >> 3)) * 4096 + chunkOff;

  // B fragment stream: tile T at bFrag + T*16384 elems; frag fi at +fi*512.
  const ushort* bFrag = Wp2 + (size_t)bn * 64 * 16384 + wn * 4096 + lane * 8;

  f32x4 acc[8][4];
#pragma unroll
  for (int i = 0; i < 8; i++)
#pragma unroll
    for (int j = 0; j < 4; j++) acc[i][j] = (f32x4){0.f, 0.f, 0.f, 0.f};

  bf16x8 bA[8], bB[8];

  // Prologue: B frags of tile 0 -> bA; stage A(0) -> buf0.
  LDB(0, bA);
  STGA(0, 0);
  asm volatile("s_waitcnt vmcnt(0)" ::: "memory");
  __builtin_amdgcn_s_barrier();

#pragma unroll 1
  for (int T = 0; T < 62; T += 2) {
    TILEX(T, 0, 16384, bA, bB, false);
    TILEX(T + 1, 16384, 0, bB, bA, false);
  }
  TILEX(62, 0, 16384, bA, bB, false);   // loads bB(63), stages A(63)
  TILEX(63, 16384, 0, bB, bA, true);    // drain-free last tile

  // Fused LSTM epilogue: acc[mi][gate] register-local per (row, hcol).
  const int hcol = bn * 64 + wn * 16 + laneRow;
  const float bI = bii[hcol] + bhi[hcol];
  const float bF = bif_[hcol] + bhf[hcol];
  const float bG = big_[hcol] + bhg[hcol];
  const float bO = bio_[hcol] + bho[hcol];
#pragma unroll
  for (int mi = 0; mi < 8; ++mi) {
    const int rowBase = bm * 256 + wm * 128 + mi * 16 + lane16 * 4;
#pragma unroll
    for (int rr = 0; rr < 4; ++rr) {
      const int row = rowBase + rr;
      const float ii = acc[mi][0][rr] + bI;
      const float ff = acc[mi][1][rr] + bF;
      const float gg = acc[mi][2][rr] + bG;
      const float oo = acc[mi][3][rr] + bO;
      const float iv = 1.f / (1.f + __expf(-ii));
      const float fv = 1.f / (1.f + __expf(-ff));
      const float gv = tanhf(gg);
      const float ov = 1.f / (1.f + __expf(-oo));
      const float cv = c[(size_t)row * 2048 + hcol];
      const float cn = fv * cv + iv * gv;
      const float hn = ov * tanhf(cn);
      out[(size_t)row * 2048 + hcol] = hn;
      out[(size_t)8388608 + (size_t)row * 2048 + hcol] = cn;
    }
  }
}

extern "C" void kernel_launch(void* const* d_in, const int* in_sizes, int n_in,
                              void* d_out, int out_size, void* d_ws, size_t ws_size,
                              hipStream_t stream) {
  const float* x = (const float*)d_in[0];
  const float* h = (const float*)d_in[1];
  const float* c = (const float*)d_in[2];
  const float* Wii = (const float*)d_in[3];  const float* bii = (const float*)d_in[4];
  const float* Wif = (const float*)d_in[5];  const float* bif_ = (const float*)d_in[6];
  const float* Wig = (const float*)d_in[7];  const float* big_ = (const float*)d_in[8];
  const float* Wio = (const float*)d_in[9];  const float* bio_ = (const float*)d_in[10];
  const float* Whi = (const float*)d_in[11]; const float* bhi = (const float*)d_in[12];
  const float* Whf = (const float*)d_in[13]; const float* bhf = (const float*)d_in[14];
  const float* Whg = (const float*)d_in[15]; const float* bhg = (const float*)d_in[16];
  const float* Who = (const float*)d_in[17]; const float* bho = (const float*)d_in[18];

  ushort* Abf = (ushort*)d_ws;                    // 4096*4096 bf16 = 32 MB
  ushort* Wpk = Abf + (size_t)4096 * 4096;        // fragment-linear, 64 MB
  float* out = (float*)d_out;

  pack_all_kernel<<<3072, 256, 0, stream>>>((const float4*)x, (const float4*)h,
                                            Wii, Wif, Wig, Wio, Whi, Whf, Whg, Who,
                                            (ushort4*)Abf, Wpk);
  lstm_gemm_kernel<<<512, 512, 0, stream>>>(Abf, Wpk, c,
                                            bii, bif_, big_, bio_, bhi, bhf, bhg, bho, out);
}

// Round 17
// 296.775 us; speedup vs baseline: 1.0949x; 1.0949x over previous
//
#include <hip/hip_runtime.h>
#include <stdint.h>

typedef __attribute__((ext_vector_type(4))) float f32x4;
typedef __attribute__((ext_vector_type(8))) short bf16x8;

#define MFMA_BF16 __builtin_amdgcn_mfma_f32_16x16x32_bf16

__device__ __forceinline__ unsigned short f2bf(float f) {
  union { float f; uint32_t u; } a; a.f = f;
  uint32_t u = a.u;
  uint32_t r = (u + 0x7FFFu + ((u >> 16) & 1u)) >> 16;
  return (unsigned short)r;
}

__device__ __forceinline__ bf16x8 cvt8(const float4 v0, const float4 v1) {
  bf16x8 o;
  o[0] = (short)f2bf(v0.x); o[1] = (short)f2bf(v0.y);
  o[2] = (short)f2bf(v0.z); o[3] = (short)f2bf(v0.w);
  o[4] = (short)f2bf(v1.x); o[5] = (short)f2bf(v1.y);
  o[6] = (short)f2bf(v1.z); o[7] = (short)f2bf(v1.w);
  return o;
}

// Merged pack, 16B-write vectorized (8 bf16 per lane-iteration).
// chunk q in [0, 2097152): A ([x|h] -> bf16 A[4096][4096], row-major).
// chunk q in [2097152, 6291456): W -> gate-interleaved Wp[8192][4096]:
//   packed row p: r=p&255; gate g=((r>>7)<<1)|((r>>4)&1);
//   H=((p>>8)<<6)|(((r>>5)&3)<<4)|(r&15); cols 0..2047=Wx_g[H], 2048..=Wh_g[H].
__global__ void pack_all_kernel(const float4* __restrict__ x, const float4* __restrict__ hh,
                                const float* __restrict__ Wii, const float* __restrict__ Wif,
                                const float* __restrict__ Wig, const float* __restrict__ Wio,
                                const float* __restrict__ Whi, const float* __restrict__ Whf,
                                const float* __restrict__ Whg, const float* __restrict__ Who,
                                bf16x8* __restrict__ A, bf16x8* __restrict__ Wp) {
  const int total = 6291456;
  for (int q = blockIdx.x * blockDim.x + threadIdx.x; q < total; q += gridDim.x * blockDim.x) {
    if (q < 2097152) {
      int row = q >> 9, c8 = q & 511;   // 512 chunks of 8 per 4096-col row
      const float4* src = (c8 < 256) ? &x[row * 512 + c8 * 2] : &hh[row * 512 + (c8 - 256) * 2];
      A[q] = cvt8(src[0], src[1]);
    } else {
      int wq = q - 2097152;
      int p = wq >> 9, k8 = wq & 511;
      int r = p & 255;
      int g = ((r >> 7) << 1) | ((r >> 4) & 1);
      int H = ((p >> 8) << 6) | (((r >> 5) & 3) << 4) | (r & 15);
      const float* src;
      int k;
      if (k8 < 256) {
        src = (g == 0) ? Wii : (g == 1) ? Wif : (g == 2) ? Wig : Wio; k = k8 << 3;
      } else {
        src = (g == 0) ? Whi : (g == 1) ? Whf : (g == 2) ? Whg : Who; k = (k8 - 256) << 3;
      }
      const float4 v0 = *(const float4*)&src[(size_t)H * 2048 + k];
      const float4 v1 = *(const float4*)&src[(size_t)H * 2048 + k + 4];
      Wp[wq] = cvt8(v0, v1);
    }
  }
}

// R13 GEMM (best measured: 263 us, MfmaUtil 47.2%, 0 conflicts).
// 3-BARRIER TILE. 256x256, BK=64, 8 waves (2Mx4N), per-wave 128x64.
// LDS: 2 bufs x {A0,A1,B0,B1} halves. Per tile:
//   vmcnt(6); BAR | ph0: rd af0,b01; stg A1(T+1)->nbuf; q00 | BAR
//   ph1: rd b23; stg A0,B0(T+2)->buf; q01 | BAR
//   ph2: rd af1; stg B1(T+2)->buf; q10+q11
#define BARF asm volatile("s_barrier" ::: "memory")

#define STGH(srcH, kOff, dstE)                                                  \
  __builtin_amdgcn_global_load_lds(                                             \
      (const __attribute__((address_space(1))) void*)((srcH) + (kOff)),         \
      (__attribute__((address_space(3))) void*)(&smem[dstE]), 16, 0, 0);        \
  __builtin_amdgcn_global_load_lds(                                             \
      (const __attribute__((address_space(1))) void*)((srcH) + 32768 + (kOff)), \
      (__attribute__((address_space(3))) void*)(&smem[(dstE) + 512]), 16, 0, 0)

#define Q(ACCR, ACCC, AF_, BF_)                                                 \
  _Pragma("unroll") for (int kk = 0; kk < 2; ++kk)                              \
    _Pragma("unroll") for (int m = 0; m < 4; ++m)                               \
      _Pragma("unroll") for (int n = 0; n < 2; ++n)                             \
        acc[(ACCR) + m][(ACCC) + n] =                                           \
            MFMA_BF16(AF_[m][kk], BF_[n][kk], acc[(ACCR) + m][(ACCC) + n], 0, 0, 0);

#define TILE(bufE_, nbufE_, kA1_, kT2_, ST_A1, ST_T2, VMC)                       \
  {                                                                              \
    if ((VMC) == 6) asm volatile("s_waitcnt vmcnt(6)" ::: "memory");             \
    else            asm volatile("s_waitcnt vmcnt(0)" ::: "memory");             \
    BARF;  /* all waves' tile-T halves DMA-visible */                            \
    bf16x8 af0[4][2], af1[4][2], b01[2][2], b23[2][2];                           \
    /* ph0 */                                                                    \
    _Pragma("unroll") for (int m = 0; m < 4; ++m) {                              \
      af0[m][0] = *(const bf16x8*)&smem[(bufE_) + aR + m * 1024 + colE0];        \
      af0[m][1] = *(const bf16x8*)&smem[(bufE_) + aR + m * 1024 + colE1];        \
    }                                                                            \
    _Pragma("unroll") for (int n = 0; n < 2; ++n) {                              \
      b01[n][0] = *(const bf16x8*)&smem[(bufE_) + 16384 + bR + n * 1024 + colE0];\
      b01[n][1] = *(const bf16x8*)&smem[(bufE_) + 16384 + bR + n * 1024 + colE1];\
    }                                                                            \
    if (ST_A1) { STGH(aSrcH1, kA1_, (nbufE_) + 8192 + dstW); }                   \
    __builtin_amdgcn_s_setprio(1);                                               \
    Q(0, 0, af0, b01);                                                           \
    __builtin_amdgcn_s_setprio(0);                                               \
    BARF;  /* ph0 reads consumed -> safe to restage A0,B0 */                     \
    /* ph1 */                                                                    \
    _Pragma("unroll") for (int n = 0; n < 2; ++n) {                              \
      b23[n][0] = *(const bf16x8*)&smem[(bufE_) + 24576 + bR + n * 1024 + colE0];\
      b23[n][1] = *(const bf16x8*)&smem[(bufE_) + 24576 + bR + n * 1024 + colE1];\
    }                                                                            \
    if (ST_T2) {                                                                 \
      STGH(aSrcH0, kT2_, (bufE_) + dstW);                                        \
      STGH(bSrcH0, kT2_, (bufE_) + 16384 + dstW);                                \
    }                                                                            \
    __builtin_amdgcn_s_setprio(1);                                               \
    Q(0, 2, af0, b23);                                                           \
    __builtin_amdgcn_s_setprio(0);                                               \
    BARF;  /* ph1 reads consumed -> safe to restage B1 */                        \
    /* ph2 */                                                                    \
    _Pragma("unroll") for (int m = 0; m < 4; ++m) {                              \
      af1[m][0] = *(const bf16x8*)&smem[(bufE_) + 8192 + aR + m * 1024 + colE0]; \
      af1[m][1] = *(const bf16x8*)&smem[(bufE_) + 8192 + aR + m * 1024 + colE1]; \
    }                                                                            \
    if (ST_T2) { STGH(bSrcH1, kT2_, (bufE_) + 24576 + dstW); }                   \
    __builtin_amdgcn_s_setprio(1);                                               \
    Q(4, 0, af1, b01);                                                           \
    Q(4, 2, af1, b23);                                                           \
    __builtin_amdgcn_s_setprio(0);                                               \
  }

__global__ __launch_bounds__(512, 2)
void lstm_gemm_kernel(const ushort* __restrict__ A, const ushort* __restrict__ Wp,
                      const float* __restrict__ c,
                      const float* __restrict__ bii, const float* __restrict__ bif_,
                      const float* __restrict__ big_, const float* __restrict__ bio_,
                      const float* __restrict__ bhi, const float* __restrict__ bhf,
                      const float* __restrict__ bhg, const float* __restrict__ bho,
                      float* __restrict__ out) {
  __shared__ ushort smem[65536];  // 2 bufs x {A0,A1,B0,B1} halves x 16 KiB = 128 KiB
  const int tid = threadIdx.x;
  const int lane = tid & 63, w = tid >> 6;
  const int wm = w >> 2, wn = w & 3;

  // bn-major XCD mapping: XCD x owns bn in [x*4, x*4+4) x all 16 bm.
  const int bid = blockIdx.x;
  const int xcd = bid & 7, qq = bid >> 3;
  const int bn = (xcd << 2) | (qq >> 4);
  const int bm = qq & 15;

  const int laneRow = lane & 15, lane16 = lane >> 4;
  const int lr7 = laneRow & 7;
  const int colE0 = (lane16 ^ lr7) << 3;         // elem offset within 64-el row, kk=0
  const int colE1 = ((4 + lane16) ^ lr7) << 3;   // kk=1

  // DMA: lane l -> half-row (l>>3), phys chunk l&7 holding logical chunk
  // (l&7)^((l>>3)&7) -> pre-swizzled global source (proven 0-conflict scheme).
  const int chunkOff = ((lane & 7) ^ (lane >> 3)) << 3;
  const ushort* aSrcH0 = A + (size_t)(bm * 256 + 16 * w + (lane >> 3)) * 4096 + chunkOff;
  const ushort* aSrcH1 = aSrcH0 + (size_t)128 * 4096;
  const ushort* bSrcH0 = Wp + (size_t)(bn * 256 + 16 * w + (lane >> 3)) * 4096 + chunkOff;
  const ushort* bSrcH1 = bSrcH0 + (size_t)128 * 4096;
  const int dstW = w * 1024;  // wave's 16 rows within a half

  const int aR = (wm * 64 + laneRow) * 64;   // + buf + half + m*1024 + colE
  const int bR = (wn * 32 + laneRow) * 64;   // + buf + half + n*1024 + colE

  f32x4 acc[8][4];
#pragma unroll
  for (int i = 0; i < 8; i++)
#pragma unroll
    for (int j = 0; j < 4; j++) acc[i][j] = (f32x4){0.f, 0.f, 0.f, 0.f};

  // Prologue: T0 all 4 halves (8 loads) then T1's A0,B0,B1 (6 loads).
  // First TILE's vmcnt(6) retires exactly T0's 8.
  STGH(aSrcH0, 0, dstW);                  // A0(0)
  STGH(bSrcH0, 0, 16384 + dstW);          // B0(0)
  STGH(bSrcH1, 0, 24576 + dstW);          // B1(0)
  STGH(aSrcH1, 0, 8192 + dstW);           // A1(0)
  STGH(aSrcH0, 64, 32768 + dstW);         // A0(1)
  STGH(bSrcH0, 64, 32768 + 16384 + dstW); // B0(1)
  STGH(bSrcH1, 64, 32768 + 24576 + dstW); // B1(1)

#pragma unroll 1
  for (int T = 0; T < 62; T += 2) {
    const int kA = (T + 1) << 6, kB = (T + 2) << 6, kC = (T + 3) << 6;
    TILE(0, 32768, kA, kB, true, true, 6);
    TILE(32768, 0, kB, kC, true, true, 6);
  }
  TILE(0, 32768, 63 << 6, 0, true, false, 6);   // T=62: stage A1(63) only
  TILE(32768, 0, 0, 0, false, false, 0);        // T=63: drain

  // Fused LSTM epilogue: acc[mi][gate][rr] register-local per (row, hcol).
  const int hcol = bn * 64 + wn * 16 + laneRow;
  const float bI = bii[hcol] + bhi[hcol];
  const float bF = bif_[hcol] + bhf[hcol];
  const float bG = big_[hcol] + bhg[hcol];
  const float bO = bio_[hcol] + bho[hcol];
#pragma unroll
  for (int mi = 0; mi < 8; ++mi) {
    const int rowBase = bm * 256 + (mi >> 2) * 128 + wm * 64 + (mi & 3) * 16 + lane16 * 4;
#pragma unroll
    for (int rr = 0; rr < 4; ++rr) {
      const int row = rowBase + rr;
      const float ii = acc[mi][0][rr] + bI;
      const float ff = acc[mi][1][rr] + bF;
      const float gg = acc[mi][2][rr] + bG;
      const float oo = acc[mi][3][rr] + bO;
      const float iv = 1.f / (1.f + __expf(-ii));
      const float fv = 1.f / (1.f + __expf(-ff));
      const float gv = tanhf(gg);
      const float ov = 1.f / (1.f + __expf(-oo));
      const float cv = c[(size_t)row * 2048 + hcol];
      const float cn = fv * cv + iv * gv;
      const float hn = ov * tanhf(cn);
      out[(size_t)row * 2048 + hcol] = hn;
      out[(size_t)8388608 + (size_t)row * 2048 + hcol] = cn;
    }
  }
}

extern "C" void kernel_launch(void* const* d_in, const int* in_sizes, int n_in,
                              void* d_out, int out_size, void* d_ws, size_t ws_size,
                              hipStream_t stream) {
  const float* x = (const float*)d_in[0];
  const float* h = (const float*)d_in[1];
  const float* c = (const float*)d_in[2];
  const float* Wii = (const float*)d_in[3];  const float* bii = (const float*)d_in[4];
  const float* Wif = (const float*)d_in[5];  const float* bif_ = (const float*)d_in[6];
  const float* Wig = (const float*)d_in[7];  const float* big_ = (const float*)d_in[8];
  const float* Wio = (const float*)d_in[9];  const float* bio_ = (const float*)d_in[10];
  const float* Whi = (const float*)d_in[11]; const float* bhi = (const float*)d_in[12];
  const float* Whf = (const float*)d_in[13]; const float* bhf = (const float*)d_in[14];
  const float* Whg = (const float*)d_in[15]; const float* bhg = (const float*)d_in[16];
  const float* Who = (const float*)d_in[17]; const float* bho = (const float*)d_in[18];

  ushort* Abf = (ushort*)d_ws;                    // 4096*4096 bf16
  ushort* Wpk = Abf + (size_t)4096 * 4096;        // 8192*4096 bf16
  float* out = (float*)d_out;

  pack_all_kernel<<<3072, 256, 0, stream>>>((const float4*)x, (const float4*)h,
                                            Wii, Wif, Wig, Wio, Whi, Whf, Whg, Who,
                                            (bf16x8*)Abf, (bf16x8*)Wpk);
  lstm_gemm_kernel<<<512, 512, 0, stream>>>(Abf, Wpk, c,
                                            bii, bif_, big_, bio_, bhi, bhf, bhg, bho, out);
}